// Round 3
// baseline (487.038 us; speedup 1.0000x reference)
//
#include <hip/hip_runtime.h>

#define NB 512      // batch = attention sequence length L
#define NS 47
#define NP 48       // positions = attention "batch" N
#define DIM 32
#define NFF 2048
#define NHID 256
#define NROWS (NB * NP)   // 24576

__constant__ float POSC[NS * 3] = {
  0,3,0.5f, 0,3,1.5f, 0,3,2.5f, 0,3,3.5f, 0,3,4.5f, 0,3,5.5f,
  1,0,0, 1,6,6, 2,0,6, 2,6,0, 3,0,0, 3,6,6, 4,0,6, 4,6,0,
  5,0,0, 5,6,6, 6,0,6, 6,6,0, 7,0,0, 7,6,6, 8,0,6, 8,6,0,
  9,0,0, 9,6,6, 10,0,6, 10,6,0, 11,0,0, 11,6,6, 12,0,6, 12,6,0,
  13,0,0, 13,6,6, 14,0,6, 14,6,0, 15,0,0, 15,6,6, 16,0,6, 16,6,0,
  17,0.5f,0.5f, 17,3,0.5f, 17,5.5f,0.5f, 17,0.5f,3, 17,3,3, 17,5.5f,3,
  17,0.5f,5.5f, 17,3,5.5f, 17,5.5f,5.5f
};

// ff2_w[2][32][2048] -> w2t[2][2048][32]
__global__ __launch_bounds__(256) void prep_kernel(const float* __restrict__ w2,
                                                   float* __restrict__ w2t) {
  int idx = blockIdx.x * 256 + threadIdx.x;   // exactly 131072
  int l = idx >> 16, r = idx & 65535, f = r >> 5, j = r & 31;
  w2t[idx] = w2[l * 65536 + j * NFF + f];
}

// h[l][n][d]
__global__ __launch_bounds__(256) void embed_kernel(
    const float* __restrict__ x, const float* __restrict__ w_in, const float* __restrict__ b_in,
    const float* __restrict__ w_pos, const float* __restrict__ b_pos,
    const float* __restrict__ cls, float* __restrict__ h) {
  int idx = blockIdx.x * 256 + threadIdx.x;   // exactly 786432
  int r = idx >> 5, d = idx & 31;
  int l = r / NP, n = r - l * NP;
  float v;
  if (n == 0) {
    v = cls[d];
  } else {
    int s = n - 1;
    v = x[l * NS + s] * w_in[d] + b_in[d]
      + POSC[s * 3 + 0] * w_pos[d * 3 + 0]
      + POSC[s * 3 + 1] * w_pos[d * 3 + 1]
      + POSC[s * 3 + 2] * w_pos[d * 3 + 2] + b_pos[d];
  }
  h[idx] = v;
}

// one block = (position n, head hh, query-chunk qc of 256). Computes q/k/v on the fly.
__global__ __launch_bounds__(256, 2) void attn_kernel(
    const float* __restrict__ h, const float* __restrict__ wi, const float* __restrict__ bi,
    float* __restrict__ o) {
  __shared__ float kv[2][NB * 8];   // K rows, V rows (stride 8)
  __shared__ float wis[3 * 256];    // q/k/v weight slices, 8 rows x 32 each
  __shared__ float bis[24];

  const int bx = blockIdx.x;
  const int n = bx >> 3, hh = (bx >> 1) & 3, qc = bx & 1;
  const int t = threadIdx.x;

  for (int i = t; i < 768; i += 256) {
    int part = i >> 8, rem = i & 255;
    int jj = rem >> 5, d = rem & 31;
    wis[i] = wi[(part * 32 + hh * 8 + jj) * 32 + d];
  }
  if (t < 24) bis[t] = bi[(t >> 3) * 32 + hh * 8 + (t & 7)];
  __syncthreads();

  // phase 1: K,V for all 512 batch rows
  for (int mi = 0; mi < 2; ++mi) {
    int m = t + mi * 256;
    const float4* hrow = (const float4*)(h + (m * NP + n) * 32);
    float4 hv[8];
    #pragma unroll
    for (int i = 0; i < 8; ++i) hv[i] = hrow[i];
    #pragma unroll
    for (int jj = 0; jj < 8; ++jj) {
      float a0 = bis[8 + jj], a1 = 0.f, a2 = 0.f, a3 = 0.f;
      float b0 = bis[16 + jj], b1 = 0.f, b2 = 0.f, b3 = 0.f;
      #pragma unroll
      for (int d4 = 0; d4 < 8; ++d4) {
        float4 hvv = hv[d4];
        a0 += hvv.x * wis[256 + jj * 32 + 4 * d4 + 0];
        a1 += hvv.y * wis[256 + jj * 32 + 4 * d4 + 1];
        a2 += hvv.z * wis[256 + jj * 32 + 4 * d4 + 2];
        a3 += hvv.w * wis[256 + jj * 32 + 4 * d4 + 3];
        b0 += hvv.x * wis[512 + jj * 32 + 4 * d4 + 0];
        b1 += hvv.y * wis[512 + jj * 32 + 4 * d4 + 1];
        b2 += hvv.z * wis[512 + jj * 32 + 4 * d4 + 2];
        b3 += hvv.w * wis[512 + jj * 32 + 4 * d4 + 3];
      }
      kv[0][m * 8 + jj] = (a0 + a1) + (a2 + a3);
      kv[1][m * 8 + jj] = (b0 + b1) + (b2 + b3);
    }
  }
  __syncthreads();

  // phase 2: one query per thread, online softmax over 512 keys
  {
    const int l = qc * 256 + t;
    const float4* hrow = (const float4*)(h + (l * NP + n) * 32);
    float4 hv[8];
    #pragma unroll
    for (int i = 0; i < 8; ++i) hv[i] = hrow[i];
    float q[8];
    #pragma unroll
    for (int jj = 0; jj < 8; ++jj) {
      float a0 = bis[jj], a1 = 0.f, a2 = 0.f, a3 = 0.f;
      #pragma unroll
      for (int d4 = 0; d4 < 8; ++d4) {
        float4 hvv = hv[d4];
        a0 += hvv.x * wis[jj * 32 + 4 * d4 + 0];
        a1 += hvv.y * wis[jj * 32 + 4 * d4 + 1];
        a2 += hvv.z * wis[jj * 32 + 4 * d4 + 2];
        a3 += hvv.w * wis[jj * 32 + 4 * d4 + 3];
      }
      q[jj] = (a0 + a1) + (a2 + a3);
    }
    float mx = -1e30f, sum = 0.f;
    float oa[8];
    #pragma unroll
    for (int d = 0; d < 8; ++d) oa[d] = 0.f;
    #pragma unroll 2
    for (int m = 0; m < NB; ++m) {
      const float4* kr = (const float4*)&kv[0][m * 8];
      float4 k0 = kr[0], k1 = kr[1];
      float s = q[0] * k0.x + q[1] * k0.y + q[2] * k0.z + q[3] * k0.w
              + q[4] * k1.x + q[5] * k1.y + q[6] * k1.z + q[7] * k1.w;
      s *= 0.35355339059327373f;
      float mn = fmaxf(mx, s);
      float alpha = __expf(mx - mn);
      float p = __expf(s - mn);
      sum = sum * alpha + p;
      const float4* vr = (const float4*)&kv[1][m * 8];
      float4 v0 = vr[0], v1 = vr[1];
      oa[0] = oa[0] * alpha + p * v0.x; oa[1] = oa[1] * alpha + p * v0.y;
      oa[2] = oa[2] * alpha + p * v0.z; oa[3] = oa[3] * alpha + p * v0.w;
      oa[4] = oa[4] * alpha + p * v1.x; oa[5] = oa[5] * alpha + p * v1.y;
      oa[6] = oa[6] * alpha + p * v1.z; oa[7] = oa[7] * alpha + p * v1.w;
      mx = mn;
    }
    float inv = 1.f / sum;
    float* orow = o + (l * NP + n) * 32 + hh * 8;
    float4* o4 = (float4*)orow;
    o4[0] = make_float4(oa[0] * inv, oa[1] * inv, oa[2] * inv, oa[3] * inv);
    o4[1] = make_float4(oa[4] * inv, oa[5] * inv, oa[6] * inv, oa[7] * inv);
  }
}

// out-proj + residual + LN1, in-place on h. Block = 64 rows.
__global__ __launch_bounds__(256) void proj_ln1_kernel(
    const float* __restrict__ o, const float* __restrict__ wo, const float* __restrict__ bo,
    const float* __restrict__ lw, const float* __restrict__ lb, float* __restrict__ h) {
  __shared__ float wos[32 * 33];
  __shared__ float pre[64 * 33];
  const int g = blockIdx.x, t = threadIdx.x;
  for (int i = t; i < 1024; i += 256) wos[(i >> 5) * 33 + (i & 31)] = wo[i];
  __syncthreads();
  const int subr = t >> 2, jq = t & 3;
  const int r = g * 64 + subr;
  const float4* orow = (const float4*)(o + r * 32);
  float4 ov[8];
  #pragma unroll
  for (int i = 0; i < 8; ++i) ov[i] = orow[i];
  const float* hres = h + r * 32 + jq * 8;
  #pragma unroll
  for (int jj = 0; jj < 8; ++jj) {
    int j = jq * 8 + jj;
    float a0 = bo[j], a1 = 0.f, a2 = 0.f, a3 = 0.f;
    #pragma unroll
    for (int d4 = 0; d4 < 8; ++d4) {
      float4 vv = ov[d4];
      a0 += vv.x * wos[j * 33 + 4 * d4 + 0];
      a1 += vv.y * wos[j * 33 + 4 * d4 + 1];
      a2 += vv.z * wos[j * 33 + 4 * d4 + 2];
      a3 += vv.w * wos[j * 33 + 4 * d4 + 3];
    }
    pre[subr * 33 + j] = (a0 + a1) + (a2 + a3) + hres[jj];
  }
  __syncthreads();
  if (t < 64) {
    float mu = 0.f;
    #pragma unroll
    for (int d = 0; d < 32; ++d) mu += pre[t * 33 + d];
    mu *= (1.f / 32.f);
    float var = 0.f;
    #pragma unroll
    for (int d = 0; d < 32; ++d) { float dv = pre[t * 33 + d] - mu; var += dv * dv; }
    float rs = rsqrtf(var * (1.f / 32.f) + 1e-5f);
    float* hrow = h + (g * 64 + t) * 32;
    #pragma unroll
    for (int d = 0; d < 32; ++d)
      hrow[d] = (pre[t * 33 + d] - mu) * rs * lw[d] + lb[d];
  }
}

// FF partial: block (rowgroup of 64, ff-half c). lane=row, wave owns 256 ff.
// Per-wave partials reduced across the block's 4 waves in LDS before the
// single yp write (round-2 bug: waves clobbered each other's yp row).
__global__ __launch_bounds__(256) void ff_partial_kernel(
    const float* __restrict__ h, const float* __restrict__ w1, const float* __restrict__ b1,
    const float* __restrict__ w2t, float* __restrict__ yp) {
  __shared__ float hl[64 * 33];
  __shared__ float yw[4 * 64 * 33];   // per-wave y partials, stride 33
  const int bx = blockIdx.x;
  const int rowg = bx >> 1, c = bx & 1;
  const int r0 = rowg * 64;
  const int t = threadIdx.x;
  for (int i = t; i < 2048; i += 256) hl[(i >> 5) * 33 + (i & 31)] = h[r0 * 32 + i];
  __syncthreads();
  const int lane = t & 63;
  const int wv = __builtin_amdgcn_readfirstlane(t >> 6);
  float hr[32];
  #pragma unroll
  for (int d = 0; d < 32; ++d) hr[d] = hl[lane * 33 + d];
  float y[32];
  #pragma unroll
  for (int j = 0; j < 32; ++j) y[j] = 0.f;
  const int ffA = c * 1024 + wv * 256;
  const float* __restrict__ w1b = w1 + ffA * 32;
  const float* __restrict__ w2b = w2t + ffA * 32;
  const float* __restrict__ b1b = b1 + ffA;
  for (int ff = 0; ff < 256; ++ff) {
    const float4* w1v = (const float4*)(w1b + ff * 32);
    float u0 = b1b[ff], u1 = 0.f, u2 = 0.f, u3 = 0.f;
    #pragma unroll
    for (int d4 = 0; d4 < 8; ++d4) {
      float4 w = w1v[d4];
      u0 += hr[4 * d4 + 0] * w.x; u1 += hr[4 * d4 + 1] * w.y;
      u2 += hr[4 * d4 + 2] * w.z; u3 += hr[4 * d4 + 3] * w.w;
    }
    float u = fmaxf((u0 + u1) + (u2 + u3), 0.f);
    const float4* w2v = (const float4*)(w2b + ff * 32);
    #pragma unroll
    for (int j4 = 0; j4 < 8; ++j4) {
      float4 w = w2v[j4];
      y[4 * j4 + 0] += u * w.x; y[4 * j4 + 1] += u * w.y;
      y[4 * j4 + 2] += u * w.z; y[4 * j4 + 3] += u * w.w;
    }
  }
  #pragma unroll
  for (int j = 0; j < 32; ++j) yw[wv * 2112 + lane * 33 + j] = y[j];
  __syncthreads();
  {
    const int subr = t >> 2, jq = t & 3;
    float v[8];
    #pragma unroll
    for (int jj = 0; jj < 8; ++jj) {
      int off = subr * 33 + jq * 8 + jj;
      v[jj] = yw[off] + yw[2112 + off] + yw[2 * 2112 + off] + yw[3 * 2112 + off];
    }
    float4* yrow = (float4*)(yp + (c * NROWS + r0 + subr) * 32 + jq * 8);
    yrow[0] = make_float4(v[0], v[1], v[2], v[3]);
    yrow[1] = make_float4(v[4], v[5], v[6], v[7]);
  }
}

// reduce 2 FF partials + bias + residual + LN2 (in-place h); optionally svec.
__global__ __launch_bounds__(256) void ffred_ln2_kernel(
    const float* __restrict__ yp, const float* __restrict__ b2,
    const float* __restrict__ lw, const float* __restrict__ lb, float* __restrict__ h,
    const float* __restrict__ ow, const float* __restrict__ ob,
    float* __restrict__ svec, int do_svec) {
  __shared__ float pre[64 * 33];
  const int g = blockIdx.x, t = threadIdx.x;
  const int subr = t >> 2, jq = t & 3;
  const int r = g * 64 + subr;
  const float4* y0 = (const float4*)(yp + r * 32 + jq * 8);
  const float4* y1 = (const float4*)(yp + (NROWS + r) * 32 + jq * 8);
  const float4* hres = (const float4*)(h + r * 32 + jq * 8);
  const float4* b2v = (const float4*)(b2 + jq * 8);
  #pragma unroll
  for (int i = 0; i < 2; ++i) {
    float4 a = y0[i], b = y1[i], c = hres[i], bb = b2v[i];
    pre[subr * 33 + jq * 8 + 4 * i + 0] = a.x + b.x + c.x + bb.x;
    pre[subr * 33 + jq * 8 + 4 * i + 1] = a.y + b.y + c.y + bb.y;
    pre[subr * 33 + jq * 8 + 4 * i + 2] = a.z + b.z + c.z + bb.z;
    pre[subr * 33 + jq * 8 + 4 * i + 3] = a.w + b.w + c.w + bb.w;
  }
  __syncthreads();
  if (t < 64) {
    float mu = 0.f;
    #pragma unroll
    for (int d = 0; d < 32; ++d) mu += pre[t * 33 + d];
    mu *= (1.f / 32.f);
    float var = 0.f;
    #pragma unroll
    for (int d = 0; d < 32; ++d) { float dv = pre[t * 33 + d] - mu; var += dv * dv; }
    float rs = rsqrtf(var * (1.f / 32.f) + 1e-5f);
    const int rr = g * 64 + t;
    float* hrow = h + rr * 32;
    float hn[32];
    #pragma unroll
    for (int d = 0; d < 32; ++d) {
      hn[d] = (pre[t * 33 + d] - mu) * rs * lw[d] + lb[d];
      hrow[d] = hn[d];
    }
    if (do_svec) {
      int l = rr / NP, n = rr - l * NP;
      if (n > 0) {
        float a = ob[0];
        #pragma unroll
        for (int d = 0; d < 32; ++d) a += hn[d] * ow[d];
        svec[l * NS + (n - 1)] = fmaxf(a, 0.f);
      }
    }
  }
}

// final MLP head per batch element
__global__ __launch_bounds__(256) void head_kernel(
    const float* __restrict__ svec,
    const float* __restrict__ m0w, const float* __restrict__ m0b,
    const float* __restrict__ m1w, const float* __restrict__ m1b,
    const float* __restrict__ m2w, const float* __restrict__ m2b,
    float* __restrict__ out) {
  __shared__ float sv[NS];
  __shared__ float hid[NHID];
  __shared__ float red[4];
  const int l = blockIdx.x, t = threadIdx.x;
  if (t < NS) sv[t] = svec[l * NS + t];
  __syncthreads();
  {
    float a = m0b[t];
    const float* wr = m0w + t * NS;
    #pragma unroll
    for (int s = 0; s < NS; ++s) a += sv[s] * wr[s];
    hid[t] = fmaxf(a, 0.f);
  }
  __syncthreads();
  {
    float a = m1b[t];
    const float4* wr = (const float4*)(m1w + t * NHID);
    #pragma unroll 8
    for (int j4 = 0; j4 < 64; ++j4) {
      float4 w = wr[j4];
      a += hid[4 * j4 + 0] * w.x + hid[4 * j4 + 1] * w.y
         + hid[4 * j4 + 2] * w.z + hid[4 * j4 + 3] * w.w;
    }
    float h2 = fmaxf(a, 0.f);
    float part = h2 * m2w[t];
    #pragma unroll
    for (int off = 32; off > 0; off >>= 1) part += __shfl_down(part, off, 64);
    if ((t & 63) == 0) red[t >> 6] = part;
  }
  __syncthreads();
  if (t == 0) out[l] = fmaxf(red[0] + red[1] + red[2] + red[3] + m2b[0], 0.f);
}

extern "C" void kernel_launch(void* const* d_in, const int* in_sizes, int n_in,
                              void* d_out, int out_size, void* d_ws, size_t ws_size,
                              hipStream_t stream) {
  (void)in_sizes; (void)n_in; (void)out_size; (void)ws_size;
  const float* x     = (const float*)d_in[0];
  const float* w_in  = (const float*)d_in[1];
  const float* b_in  = (const float*)d_in[2];
  const float* w_pos = (const float*)d_in[3];
  const float* b_pos = (const float*)d_in[4];
  const float* cls   = (const float*)d_in[5];
  const float* wi    = (const float*)d_in[6];
  const float* bi    = (const float*)d_in[7];
  const float* wo    = (const float*)d_in[8];
  const float* bo    = (const float*)d_in[9];
  const float* l1w   = (const float*)d_in[10];
  const float* l1b   = (const float*)d_in[11];
  const float* f1w   = (const float*)d_in[12];
  const float* f1b   = (const float*)d_in[13];
  const float* f2w   = (const float*)d_in[14];
  const float* f2b   = (const float*)d_in[15];
  const float* l2w   = (const float*)d_in[16];
  const float* l2b   = (const float*)d_in[17];
  const float* ow    = (const float*)d_in[18];
  const float* ob    = (const float*)d_in[19];
  const float* m0w   = (const float*)d_in[20];
  const float* m0b   = (const float*)d_in[21];
  const float* m1w   = (const float*)d_in[22];
  const float* m1b   = (const float*)d_in[23];
  const float* m2w   = (const float*)d_in[24];
  const float* m2b   = (const float*)d_in[25];
  float* out = (float*)d_out;

  float* ws   = (float*)d_ws;
  float* h    = ws;                        // 786432
  float* o    = ws + 786432;               // 786432
  float* yp   = ws + 1572864;              // 1572864
  float* svec = ws + 3145728;              // 24064
  float* w2t  = ws + 3169792;              // 131072  (total ~12.6 MiB)

  prep_kernel<<<512, 256, 0, stream>>>(f2w, w2t);
  embed_kernel<<<3072, 256, 0, stream>>>(x, w_in, b_in, w_pos, b_pos, cls, h);
  for (int L = 0; L < 2; ++L) {
    attn_kernel<<<384, 256, 0, stream>>>(h, wi + L * 3072, bi + L * 96, o);
    proj_ln1_kernel<<<384, 256, 0, stream>>>(o, wo + L * 1024, bo + L * 32,
                                             l1w + L * 32, l1b + L * 32, h);
    ff_partial_kernel<<<768, 256, 0, stream>>>(h, f1w + L * 65536, f1b + L * 2048,
                                               w2t + L * 65536, yp);
    ffred_ln2_kernel<<<384, 256, 0, stream>>>(yp, f2b + L * 32, l2w + L * 32, l2b + L * 32,
                                              h, ow, ob, svec, L);
  }
  head_kernel<<<512, 256, 0, stream>>>(svec, m0w, m0b, m1w, m1b, m2w, m2b, out);
}

// Round 4
// 333.427 us; speedup vs baseline: 1.4607x; 1.4607x over previous
//
#include <hip/hip_runtime.h>

#define NB 512      // batch = attention sequence length L
#define NS 47
#define NP 48       // positions = attention "batch" N
#define DIM 32
#define NFF 2048
#define NHID 256
#define NROWS (NB * NP)   // 24576

typedef _Float16 f16x8 __attribute__((ext_vector_type(8)));
typedef _Float16 f16x4 __attribute__((ext_vector_type(4)));
typedef float f32x4 __attribute__((ext_vector_type(4)));

__constant__ float POSC[NS * 3] = {
  0,3,0.5f, 0,3,1.5f, 0,3,2.5f, 0,3,3.5f, 0,3,4.5f, 0,3,5.5f,
  1,0,0, 1,6,6, 2,0,6, 2,6,0, 3,0,0, 3,6,6, 4,0,6, 4,6,0,
  5,0,0, 5,6,6, 6,0,6, 6,6,0, 7,0,0, 7,6,6, 8,0,6, 8,6,0,
  9,0,0, 9,6,6, 10,0,6, 10,6,0, 11,0,0, 11,6,6, 12,0,6, 12,6,0,
  13,0,0, 13,6,6, 14,0,6, 14,6,0, 15,0,0, 15,6,6, 16,0,6, 16,6,0,
  17,0.5f,0.5f, 17,3,0.5f, 17,5.5f,0.5f, 17,0.5f,3, 17,3,3, 17,5.5f,3,
  17,0.5f,5.5f, 17,3,5.5f, 17,5.5f,5.5f
};

__device__ __forceinline__ unsigned pkh2(float a, float b) {
  union { _Float16 f; unsigned short u; } x, y;
  x.f = (_Float16)a; y.f = (_Float16)b;
  return (unsigned)x.u | ((unsigned)y.u << 16);
}

// convert f1w[2][2048][32] and f2w[2][32][2048] to fp16, same layouts
__global__ __launch_bounds__(256) void prep16_kernel(const float* __restrict__ w1,
                                                     const float* __restrict__ w2,
                                                     _Float16* __restrict__ w1h,
                                                     _Float16* __restrict__ w2h) {
  int idx = blockIdx.x * 256 + threadIdx.x;   // exactly 131072
  w1h[idx] = (_Float16)w1[idx];
  w2h[idx] = (_Float16)w2[idx];
}

// h[l][n][d]
__global__ __launch_bounds__(256) void embed_kernel(
    const float* __restrict__ x, const float* __restrict__ w_in, const float* __restrict__ b_in,
    const float* __restrict__ w_pos, const float* __restrict__ b_pos,
    const float* __restrict__ cls, float* __restrict__ h) {
  int idx = blockIdx.x * 256 + threadIdx.x;   // exactly 786432
  int r = idx >> 5, d = idx & 31;
  int l = r / NP, n = r - l * NP;
  float v;
  if (n == 0) {
    v = cls[d];
  } else {
    int s = n - 1;
    v = x[l * NS + s] * w_in[d] + b_in[d]
      + POSC[s * 3 + 0] * w_pos[d * 3 + 0]
      + POSC[s * 3 + 1] * w_pos[d * 3 + 1]
      + POSC[s * 3 + 2] * w_pos[d * 3 + 2] + b_pos[d];
  }
  h[idx] = v;
}

// one block = (position n, head hh, query-chunk qc of 256). Computes q/k/v on the fly.
__global__ __launch_bounds__(256, 2) void attn_kernel(
    const float* __restrict__ h, const float* __restrict__ wi, const float* __restrict__ bi,
    float* __restrict__ o) {
  __shared__ float kv[2][NB * 8];   // K rows, V rows (stride 8)
  __shared__ float wis[3 * 256];    // q/k/v weight slices, 8 rows x 32 each
  __shared__ float bis[24];

  const int bx = blockIdx.x;
  const int n = bx >> 3, hh = (bx >> 1) & 3, qc = bx & 1;
  const int t = threadIdx.x;

  for (int i = t; i < 768; i += 256) {
    int part = i >> 8, rem = i & 255;
    int jj = rem >> 5, d = rem & 31;
    wis[i] = wi[(part * 32 + hh * 8 + jj) * 32 + d];
  }
  if (t < 24) bis[t] = bi[(t >> 3) * 32 + hh * 8 + (t & 7)];
  __syncthreads();

  // phase 1: K,V for all 512 batch rows
  for (int mi = 0; mi < 2; ++mi) {
    int m = t + mi * 256;
    const float4* hrow = (const float4*)(h + (m * NP + n) * 32);
    float4 hv[8];
    #pragma unroll
    for (int i = 0; i < 8; ++i) hv[i] = hrow[i];
    #pragma unroll
    for (int jj = 0; jj < 8; ++jj) {
      float a0 = bis[8 + jj], a1 = 0.f, a2 = 0.f, a3 = 0.f;
      float b0 = bis[16 + jj], b1 = 0.f, b2 = 0.f, b3 = 0.f;
      #pragma unroll
      for (int d4 = 0; d4 < 8; ++d4) {
        float4 hvv = hv[d4];
        a0 += hvv.x * wis[256 + jj * 32 + 4 * d4 + 0];
        a1 += hvv.y * wis[256 + jj * 32 + 4 * d4 + 1];
        a2 += hvv.z * wis[256 + jj * 32 + 4 * d4 + 2];
        a3 += hvv.w * wis[256 + jj * 32 + 4 * d4 + 3];
        b0 += hvv.x * wis[512 + jj * 32 + 4 * d4 + 0];
        b1 += hvv.y * wis[512 + jj * 32 + 4 * d4 + 1];
        b2 += hvv.z * wis[512 + jj * 32 + 4 * d4 + 2];
        b3 += hvv.w * wis[512 + jj * 32 + 4 * d4 + 3];
      }
      kv[0][m * 8 + jj] = (a0 + a1) + (a2 + a3);
      kv[1][m * 8 + jj] = (b0 + b1) + (b2 + b3);
    }
  }
  __syncthreads();

  // phase 2: one query per thread, online softmax over 512 keys
  {
    const int l = qc * 256 + t;
    const float4* hrow = (const float4*)(h + (l * NP + n) * 32);
    float4 hv[8];
    #pragma unroll
    for (int i = 0; i < 8; ++i) hv[i] = hrow[i];
    float q[8];
    #pragma unroll
    for (int jj = 0; jj < 8; ++jj) {
      float a0 = bis[jj], a1 = 0.f, a2 = 0.f, a3 = 0.f;
      #pragma unroll
      for (int d4 = 0; d4 < 8; ++d4) {
        float4 hvv = hv[d4];
        a0 += hvv.x * wis[jj * 32 + 4 * d4 + 0];
        a1 += hvv.y * wis[jj * 32 + 4 * d4 + 1];
        a2 += hvv.z * wis[jj * 32 + 4 * d4 + 2];
        a3 += hvv.w * wis[jj * 32 + 4 * d4 + 3];
      }
      q[jj] = (a0 + a1) + (a2 + a3);
    }
    float mx = -1e30f, sum = 0.f;
    float oa[8];
    #pragma unroll
    for (int d = 0; d < 8; ++d) oa[d] = 0.f;
    for (int m = 0; m < NB; ++m) {
      const float4* kr = (const float4*)&kv[0][m * 8];
      float4 k0 = kr[0], k1 = kr[1];
      float s = q[0] * k0.x + q[1] * k0.y + q[2] * k0.z + q[3] * k0.w
              + q[4] * k1.x + q[5] * k1.y + q[6] * k1.z + q[7] * k1.w;
      s *= 0.35355339059327373f;
      const float4* vr = (const float4*)&kv[1][m * 8];
      float4 v0 = vr[0], v1 = vr[1];
      if (__all(s <= mx)) {
        // fast path: max unchanged, alpha == 1 exactly -> identical numerics
        float p = __expf(s - mx);
        sum += p;
        oa[0] += p * v0.x; oa[1] += p * v0.y; oa[2] += p * v0.z; oa[3] += p * v0.w;
        oa[4] += p * v1.x; oa[5] += p * v1.y; oa[6] += p * v1.z; oa[7] += p * v1.w;
      } else {
        float mn = fmaxf(mx, s);
        float alpha = __expf(mx - mn);
        float p = __expf(s - mn);
        sum = sum * alpha + p;
        oa[0] = oa[0] * alpha + p * v0.x; oa[1] = oa[1] * alpha + p * v0.y;
        oa[2] = oa[2] * alpha + p * v0.z; oa[3] = oa[3] * alpha + p * v0.w;
        oa[4] = oa[4] * alpha + p * v1.x; oa[5] = oa[5] * alpha + p * v1.y;
        oa[6] = oa[6] * alpha + p * v1.z; oa[7] = oa[7] * alpha + p * v1.w;
        mx = mn;
      }
    }
    float inv = 1.f / sum;
    float* orow = o + (l * NP + n) * 32 + hh * 8;
    float4* o4 = (float4*)orow;
    o4[0] = make_float4(oa[0] * inv, oa[1] * inv, oa[2] * inv, oa[3] * inv);
    o4[1] = make_float4(oa[4] * inv, oa[5] * inv, oa[6] * inv, oa[7] * inv);
  }
}

// out-proj + residual + LN1, in-place on h; also emits fp16 copy h16 for the FF MFMA.
__global__ __launch_bounds__(256) void proj_ln1_kernel(
    const float* __restrict__ o, const float* __restrict__ wo, const float* __restrict__ bo,
    const float* __restrict__ lw, const float* __restrict__ lb, float* __restrict__ h,
    _Float16* __restrict__ h16) {
  __shared__ float wos[32 * 33];
  __shared__ float pre[64 * 33];
  const int g = blockIdx.x, t = threadIdx.x;
  for (int i = t; i < 1024; i += 256) wos[(i >> 5) * 33 + (i & 31)] = wo[i];
  __syncthreads();
  const int subr = t >> 2, jq = t & 3;
  const int r = g * 64 + subr;
  const float4* orow = (const float4*)(o + r * 32);
  float4 ov[8];
  #pragma unroll
  for (int i = 0; i < 8; ++i) ov[i] = orow[i];
  const float* hres = h + r * 32 + jq * 8;
  #pragma unroll
  for (int jj = 0; jj < 8; ++jj) {
    int j = jq * 8 + jj;
    float a0 = bo[j], a1 = 0.f, a2 = 0.f, a3 = 0.f;
    #pragma unroll
    for (int d4 = 0; d4 < 8; ++d4) {
      float4 vv = ov[d4];
      a0 += vv.x * wos[j * 33 + 4 * d4 + 0];
      a1 += vv.y * wos[j * 33 + 4 * d4 + 1];
      a2 += vv.z * wos[j * 33 + 4 * d4 + 2];
      a3 += vv.w * wos[j * 33 + 4 * d4 + 3];
    }
    pre[subr * 33 + j] = (a0 + a1) + (a2 + a3) + hres[jj];
  }
  __syncthreads();
  if (t < 64) {
    float mu = 0.f;
    #pragma unroll
    for (int d = 0; d < 32; ++d) mu += pre[t * 33 + d];
    mu *= (1.f / 32.f);
    float var = 0.f;
    #pragma unroll
    for (int d = 0; d < 32; ++d) { float dv = pre[t * 33 + d] - mu; var += dv * dv; }
    float rs = rsqrtf(var * (1.f / 32.f) + 1e-5f);
    const int rr = g * 64 + t;
    float* hrow = h + rr * 32;
    float hn[32];
    #pragma unroll
    for (int d = 0; d < 32; ++d) {
      hn[d] = (pre[t * 33 + d] - mu) * rs * lw[d] + lb[d];
      hrow[d] = hn[d];
    }
    uint4* h16row = (uint4*)(h16 + rr * 32);
    #pragma unroll
    for (int q4 = 0; q4 < 4; ++q4) {
      uint4 qq;
      qq.x = pkh2(hn[q4 * 8 + 0], hn[q4 * 8 + 1]);
      qq.y = pkh2(hn[q4 * 8 + 2], hn[q4 * 8 + 3]);
      qq.z = pkh2(hn[q4 * 8 + 4], hn[q4 * 8 + 5]);
      qq.w = pkh2(hn[q4 * 8 + 6], hn[q4 * 8 + 7]);
      h16row[q4] = qq;
    }
  }
}

// Fused FF via fp16 MFMA. Block = 2 waves x 16 token rows = 32 rows; grid 768 (exact 3/CU).
// GEMM1 (swapped): u_tile[ff][tok] = mfma(w1frag, hfrag); +bias, relu, ->fp16 ->LDS.
// GEMM2: y[tok][dim] += mfma(ufrag, w2frag). y written fp32 to yp (full, not partial).
__global__ __launch_bounds__(128) void ff_mfma_kernel(
    const _Float16* __restrict__ h16, const _Float16* __restrict__ w1h,
    const float* __restrict__ b1, const _Float16* __restrict__ w2h,
    float* __restrict__ yp) {
  __shared__ _Float16 ubuf[2 * 16 * 40];   // per-wave [16 tok][40-stride ff halfs]
  const int t = threadIdx.x;
  const int lane = t & 63;
  const int wv = t >> 6;
  const int nl = lane & 15;     // tok col (GEMM1 C / GEMM2 A) or dim col (GEMM2 B)
  const int g = lane >> 4;      // k-group
  const int g4 = g * 4;
  const int r0 = blockIdx.x * 32 + wv * 16;   // this wave's 16 token rows
  _Float16* ub = ubuf + wv * 640;

  // B-frag of GEMM1: h16[tok = r0+nl][k = g*8 .. g*8+7], reused for all chunks
  const f16x8 hfrag = *(const f16x8*)(h16 + (r0 + nl) * 32 + g * 8);

  f32x4 acc0 = {0.f, 0.f, 0.f, 0.f};   // y dims 0-15
  f32x4 acc1 = {0.f, 0.f, 0.f, 0.f};   // y dims 16-31
  const f32x4 zero = {0.f, 0.f, 0.f, 0.f};

  for (int ch = 0; ch < 64; ++ch) {
    const int ffb = ch * 32;
    // ---- GEMM1: two 16-ff tiles -> u in LDS (fp16) ----
    #pragma unroll
    for (int ft = 0; ft < 2; ++ft) {
      const int ffr = ffb + ft * 16;
      f16x8 afrag = *(const f16x8*)(w1h + (ffr + nl) * 32 + g * 8);
      f32x4 c = __builtin_amdgcn_mfma_f32_16x16x32_f16(afrag, hfrag, zero, 0, 0, 0);
      float4 bv = *(const float4*)(b1 + ffr + g4);   // C rows = ff = ffr + g*4 + r
      f16x4 uv;
      uv[0] = (_Float16)fmaxf(c[0] + bv.x, 0.f);
      uv[1] = (_Float16)fmaxf(c[1] + bv.y, 0.f);
      uv[2] = (_Float16)fmaxf(c[2] + bv.z, 0.f);
      uv[3] = (_Float16)fmaxf(c[3] + bv.w, 0.f);
      *(f16x4*)(ub + nl * 40 + ft * 16 + g4) = uv;   // [tok=nl][ff-in-chunk]
    }
    // ---- GEMM2: A = u (tok x 32ff), B = w2 (32ff x dim), two dim tiles ----
    f16x8 ufrag = *(const f16x8*)(ub + nl * 40 + g * 8);
    {
      f16x8 b0 = *(const f16x8*)(w2h + nl * NFF + ffb + g * 8);
      acc0 = __builtin_amdgcn_mfma_f32_16x16x32_f16(ufrag, b0, acc0, 0, 0, 0);
      f16x8 b1f = *(const f16x8*)(w2h + (16 + nl) * NFF + ffb + g * 8);
      acc1 = __builtin_amdgcn_mfma_f32_16x16x32_f16(ufrag, b1f, acc1, 0, 0, 0);
    }
  }
  // store y: C layout col=nl(dim within tile), row=g*4+r (tok within 16)
  #pragma unroll
  for (int r = 0; r < 4; ++r) {
    yp[(r0 + g4 + r) * 32 + nl] = acc0[r];
    yp[(r0 + g4 + r) * 32 + 16 + nl] = acc1[r];
  }
}

// FF y + bias + residual + LN2 (in-place h); optionally svec.
__global__ __launch_bounds__(256) void ffred_ln2_kernel(
    const float* __restrict__ yp, const float* __restrict__ b2,
    const float* __restrict__ lw, const float* __restrict__ lb, float* __restrict__ h,
    const float* __restrict__ ow, const float* __restrict__ ob,
    float* __restrict__ svec, int do_svec) {
  __shared__ float pre[64 * 33];
  const int g = blockIdx.x, t = threadIdx.x;
  const int subr = t >> 2, jq = t & 3;
  const int r = g * 64 + subr;
  const float4* y0 = (const float4*)(yp + r * 32 + jq * 8);
  const float4* hres = (const float4*)(h + r * 32 + jq * 8);
  const float4* b2v = (const float4*)(b2 + jq * 8);
  #pragma unroll
  for (int i = 0; i < 2; ++i) {
    float4 a = y0[i], c = hres[i], bb = b2v[i];
    pre[subr * 33 + jq * 8 + 4 * i + 0] = a.x + c.x + bb.x;
    pre[subr * 33 + jq * 8 + 4 * i + 1] = a.y + c.y + bb.y;
    pre[subr * 33 + jq * 8 + 4 * i + 2] = a.z + c.z + bb.z;
    pre[subr * 33 + jq * 8 + 4 * i + 3] = a.w + c.w + bb.w;
  }
  __syncthreads();
  if (t < 64) {
    float mu = 0.f;
    #pragma unroll
    for (int d = 0; d < 32; ++d) mu += pre[t * 33 + d];
    mu *= (1.f / 32.f);
    float var = 0.f;
    #pragma unroll
    for (int d = 0; d < 32; ++d) { float dv = pre[t * 33 + d] - mu; var += dv * dv; }
    float rs = rsqrtf(var * (1.f / 32.f) + 1e-5f);
    const int rr = g * 64 + t;
    float* hrow = h + rr * 32;
    float hn[32];
    #pragma unroll
    for (int d = 0; d < 32; ++d) {
      hn[d] = (pre[t * 33 + d] - mu) * rs * lw[d] + lb[d];
      hrow[d] = hn[d];
    }
    if (do_svec) {
      int l = rr / NP, n = rr - l * NP;
      if (n > 0) {
        float a = ob[0];
        #pragma unroll
        for (int d = 0; d < 32; ++d) a += hn[d] * ow[d];
        svec[l * NS + (n - 1)] = fmaxf(a, 0.f);
      }
    }
  }
}

// final MLP head per batch element
__global__ __launch_bounds__(256) void head_kernel(
    const float* __restrict__ svec,
    const float* __restrict__ m0w, const float* __restrict__ m0b,
    const float* __restrict__ m1w, const float* __restrict__ m1b,
    const float* __restrict__ m2w, const float* __restrict__ m2b,
    float* __restrict__ out) {
  __shared__ float sv[NS];
  __shared__ float hid[NHID];
  __shared__ float red[4];
  const int l = blockIdx.x, t = threadIdx.x;
  if (t < NS) sv[t] = svec[l * NS + t];
  __syncthreads();
  {
    float a = m0b[t];
    const float* wr = m0w + t * NS;
    #pragma unroll
    for (int s = 0; s < NS; ++s) a += sv[s] * wr[s];
    hid[t] = fmaxf(a, 0.f);
  }
  __syncthreads();
  {
    float a = m1b[t];
    const float4* wr = (const float4*)(m1w + t * NHID);
    #pragma unroll 8
    for (int j4 = 0; j4 < 64; ++j4) {
      float4 w = wr[j4];
      a += hid[4 * j4 + 0] * w.x + hid[4 * j4 + 1] * w.y
         + hid[4 * j4 + 2] * w.z + hid[4 * j4 + 3] * w.w;
    }
    float h2 = fmaxf(a, 0.f);
    float part = h2 * m2w[t];
    #pragma unroll
    for (int off = 32; off > 0; off >>= 1) part += __shfl_down(part, off, 64);
    if ((t & 63) == 0) red[t >> 6] = part;
  }
  __syncthreads();
  if (t == 0) out[l] = fmaxf(red[0] + red[1] + red[2] + red[3] + m2b[0], 0.f);
}

extern "C" void kernel_launch(void* const* d_in, const int* in_sizes, int n_in,
                              void* d_out, int out_size, void* d_ws, size_t ws_size,
                              hipStream_t stream) {
  (void)in_sizes; (void)n_in; (void)out_size; (void)ws_size;
  const float* x     = (const float*)d_in[0];
  const float* w_in  = (const float*)d_in[1];
  const float* b_in  = (const float*)d_in[2];
  const float* w_pos = (const float*)d_in[3];
  const float* b_pos = (const float*)d_in[4];
  const float* cls   = (const float*)d_in[5];
  const float* wi    = (const float*)d_in[6];
  const float* bi    = (const float*)d_in[7];
  const float* wo    = (const float*)d_in[8];
  const float* bo    = (const float*)d_in[9];
  const float* l1w   = (const float*)d_in[10];
  const float* l1b   = (const float*)d_in[11];
  const float* f1w   = (const float*)d_in[12];
  const float* f1b   = (const float*)d_in[13];
  const float* f2w   = (const float*)d_in[14];
  const float* f2b   = (const float*)d_in[15];
  const float* l2w   = (const float*)d_in[16];
  const float* l2b   = (const float*)d_in[17];
  const float* ow    = (const float*)d_in[18];
  const float* ob    = (const float*)d_in[19];
  const float* m0w   = (const float*)d_in[20];
  const float* m0b   = (const float*)d_in[21];
  const float* m1w   = (const float*)d_in[22];
  const float* m1b   = (const float*)d_in[23];
  const float* m2w   = (const float*)d_in[24];
  const float* m2b   = (const float*)d_in[25];
  float* out = (float*)d_out;

  float* ws   = (float*)d_ws;
  float* h    = ws;                          // 786432 f32
  float* o    = ws + 786432;                 // 786432 f32
  float* yp   = ws + 1572864;                // 786432 f32
  float* svec = ws + 2359296;                // 24064 f32
  _Float16* h16 = (_Float16*)(ws + 2383360); // 786432 halfs (393216 slots)
  _Float16* w1h = (_Float16*)(ws + 2776576); // 131072 halfs (65536 slots)
  _Float16* w2h = (_Float16*)(ws + 2842112); // 131072 halfs (65536 slots)
  // total 2907648 f32 = 11.6 MiB

  prep16_kernel<<<512, 256, 0, stream>>>(f1w, f2w, w1h, w2h);
  embed_kernel<<<3072, 256, 0, stream>>>(x, w_in, b_in, w_pos, b_pos, cls, h);
  for (int L = 0; L < 2; ++L) {
    attn_kernel<<<384, 256, 0, stream>>>(h, wi + L * 3072, bi + L * 96, o);
    proj_ln1_kernel<<<384, 256, 0, stream>>>(o, wo + L * 1024, bo + L * 32,
                                             l1w + L * 32, l1b + L * 32, h, h16);
    ff_mfma_kernel<<<768, 128, 0, stream>>>(h16, w1h + L * 65536, f1b + L * NFF,
                                            w2h + L * 65536, yp);
    ffred_ln2_kernel<<<384, 256, 0, stream>>>(yp, f2b + L * 32, l2w + L * 32, l2b + L * 32,
                                              h, ow, ob, svec, L);
  }
  head_kernel<<<512, 256, 0, stream>>>(svec, m0w, m0b, m1w, m1b, m2w, m2b, out);
}

// Round 6
// 212.629 us; speedup vs baseline: 2.2906x; 1.5681x over previous
//
#include <hip/hip_runtime.h>

#define NB 512      // batch = attention sequence length L
#define NS 47
#define NP 48       // positions = attention "batch" N
#define DIM 32
#define NFF 2048
#define NHID 256
#define NROWS (NB * NP)   // 24576

#define VSTR 520    // V^T LDS row stride (halfs), 1040 B = 65*16
#define PSTR 72     // P LDS row stride (halfs), 144 B = 9*16

typedef _Float16 f16x8 __attribute__((ext_vector_type(8)));
typedef _Float16 f16x4 __attribute__((ext_vector_type(4)));
typedef float f32x4 __attribute__((ext_vector_type(4)));

__constant__ float POSC[NS * 3] = {
  0,3,0.5f, 0,3,1.5f, 0,3,2.5f, 0,3,3.5f, 0,3,4.5f, 0,3,5.5f,
  1,0,0, 1,6,6, 2,0,6, 2,6,0, 3,0,0, 3,6,6, 4,0,6, 4,6,0,
  5,0,0, 5,6,6, 6,0,6, 6,6,0, 7,0,0, 7,6,6, 8,0,6, 8,6,0,
  9,0,0, 9,6,6, 10,0,6, 10,6,0, 11,0,0, 11,6,6, 12,0,6, 12,6,0,
  13,0,0, 13,6,6, 14,0,6, 14,6,0, 15,0,0, 15,6,6, 16,0,6, 16,6,0,
  17,0.5f,0.5f, 17,3,0.5f, 17,5.5f,0.5f, 17,0.5f,3, 17,3,3, 17,5.5f,3,
  17,0.5f,5.5f, 17,3,5.5f, 17,5.5f,5.5f
};

// convert f1w[2][2048][32] and f2w[2][32][2048] to fp16, same layouts
__global__ __launch_bounds__(256) void prep16_kernel(const float* __restrict__ w1,
                                                     const float* __restrict__ w2,
                                                     _Float16* __restrict__ w1h,
                                                     _Float16* __restrict__ w2h) {
  int idx = blockIdx.x * 256 + threadIdx.x;   // exactly 131072
  w1h[idx] = (_Float16)w1[idx];
  w2h[idx] = (_Float16)w2[idx];
}

// h[l][n][d]
__global__ __launch_bounds__(256) void embed_kernel(
    const float* __restrict__ x, const float* __restrict__ w_in, const float* __restrict__ b_in,
    const float* __restrict__ w_pos, const float* __restrict__ b_pos,
    const float* __restrict__ cls, float* __restrict__ h) {
  int idx = blockIdx.x * 256 + threadIdx.x;   // exactly 786432
  int r = idx >> 5, d = idx & 31;
  int l = r / NP, n = r - l * NP;
  float v;
  if (n == 0) {
    v = cls[d];
  } else {
    int s = n - 1;
    v = x[l * NS + s] * w_in[d] + b_in[d]
      + POSC[s * 3 + 0] * w_pos[d * 3 + 0]
      + POSC[s * 3 + 1] * w_pos[d * 3 + 1]
      + POSC[s * 3 + 2] * w_pos[d * 3 + 2] + b_pos[d];
  }
  h[idx] = v;
}

// K,V projection. Block = half of one (n,h): 256 rows.
//  Kp[nh][l][16] fp16 (hi 8, lo 8);  Vt[nh][8][512] fp16.
__global__ __launch_bounds__(256) void kv_kernel(
    const float* __restrict__ h, const float* __restrict__ wi, const float* __restrict__ bi,
    _Float16* __restrict__ Kp, _Float16* __restrict__ Vt) {
  __shared__ float ws_[512];
  __shared__ float bs_[16];
  const int t = threadIdx.x;
  const int nh = blockIdx.x >> 1;
  const int n = nh >> 2, hh = nh & 3;
  const int l = ((blockIdx.x & 1) << 8) | t;
  for (int i = t; i < 512; i += 256) {
    int sub = i >> 8, rem = i & 255;
    int jj = rem >> 5, d = rem & 31;
    ws_[i] = wi[((sub + 1) * 32 + hh * 8 + jj) * 32 + d];   // K rows 32..63, V rows 64..95
  }
  if (t < 16) bs_[t] = bi[((t >> 3) + 1) * 32 + hh * 8 + (t & 7)];
  __syncthreads();
  const float4* hrow = (const float4*)(h + (l * NP + n) * 32);
  float4 hv[8];
  #pragma unroll
  for (int i = 0; i < 8; ++i) hv[i] = hrow[i];
  f16x8 kh, kl_, vh;
  #pragma unroll
  for (int jj = 0; jj < 8; ++jj) {
    float k0 = bs_[jj], k1 = 0.f, k2 = 0.f, k3 = 0.f;
    float v0 = bs_[8 + jj], v1 = 0.f, v2 = 0.f, v3 = 0.f;
    #pragma unroll
    for (int d4 = 0; d4 < 8; ++d4) {
      float4 hvv = hv[d4];
      k0 += hvv.x * ws_[jj * 32 + 4 * d4 + 0];
      k1 += hvv.y * ws_[jj * 32 + 4 * d4 + 1];
      k2 += hvv.z * ws_[jj * 32 + 4 * d4 + 2];
      k3 += hvv.w * ws_[jj * 32 + 4 * d4 + 3];
      v0 += hvv.x * ws_[256 + jj * 32 + 4 * d4 + 0];
      v1 += hvv.y * ws_[256 + jj * 32 + 4 * d4 + 1];
      v2 += hvv.z * ws_[256 + jj * 32 + 4 * d4 + 2];
      v3 += hvv.w * ws_[256 + jj * 32 + 4 * d4 + 3];
    }
    float kv = (k0 + k1) + (k2 + k3);
    float vv = (v0 + v1) + (v2 + v3);
    kh[jj] = (_Float16)kv; kl_[jj] = (_Float16)(kv - (float)kh[jj]);
    vh[jj] = (_Float16)vv;
  }
  _Float16* kdst = Kp + ((size_t)nh * 512 + l) * 16;
  *(f16x8*)(kdst) = kh;
  *(f16x8*)(kdst + 8) = kl_;
  #pragma unroll
  for (int d = 0; d < 8; ++d) Vt[(size_t)nh * 4096 + d * 512 + l] = vh[d];
}

// MFMA attention. Block = (n, hh, qc of 64 queries); wave = 16-query tile.
// Q computed in-block (hi/lo fp16 split). Scores: K-slot groups
// [qh*kh, ql*kh, qh*kl, 0] -> fp32-accurate. No max-subtract (LN-bounded);
// p = exp(s*scale - 2); fp32 row-sum; PV via mfma with P through per-wave LDS.
__global__ __launch_bounds__(256, 2) void attn_mfma_kernel(
    const float* __restrict__ h, const float* __restrict__ wi, const float* __restrict__ bi,
    const _Float16* __restrict__ Kp, const _Float16* __restrict__ Vt,
    float* __restrict__ o) {
  __shared__ alignas(16) _Float16 khi[512 * 8];   // 8192 B, row stride 16 B
  __shared__ alignas(16) _Float16 klo[512 * 8];   // 8192 B
  __shared__ alignas(16) _Float16 vts[8 * VSTR];  // 8320 B
  __shared__ alignas(16) float hq_pls[2304];      // 9216 B: hq[64][36] -> pls[4][16*PSTR]
  __shared__ alignas(16) _Float16 qf[64 * 16];    // 2048 B
  __shared__ float wsq[256];                      // Wq slice, transposed [d][jj]
  __shared__ float bq[8];
  const int bx = blockIdx.x;
  const int nh = bx >> 3, qc = bx & 7;
  const int n = nh >> 2, hh = nh & 3;
  const int t = threadIdx.x;
  const int lane = t & 63, wv = t >> 6;
  const int c = lane & 15, g = lane >> 4;

  // ---- phase A: stage K hi/lo, V^T, Wq slice, and this block's 64 h rows ----
  const _Float16* kg = Kp + (size_t)nh * 8192;
  for (int r = t; r < 512; r += 256) {
    const uint4* src = (const uint4*)(kg + r * 16);
    uint4 a = src[0], b = src[1];
    *(uint4*)(khi + r * 8) = a;
    *(uint4*)(klo + r * 8) = b;
  }
  {
    const _Float16* vg = Vt + (size_t)nh * 4096;
    for (int i = t; i < 512; i += 256) {        // 512 segments of 8 halfs = full [8][512]
      int d = i >> 6, seg = i & 63;
      *(uint4*)(vts + d * VSTR + seg * 8) = *(const uint4*)(vg + d * 512 + seg * 8);
    }
  }
  wsq[t] = wi[(hh * 8 + (t & 7)) * 32 + (t >> 3)];   // wsq[d*8+jj] = Wq[jj][d]
  if (t < 8) bq[t] = bi[hh * 8 + t];
  float* hq = hq_pls;
  {
    int row = t >> 2, quar = t & 3;
    const float4* src = (const float4*)(h + (((qc * 64 + row) * NP) + n) * 32 + quar * 8);
    *(float4*)(hq + row * 36 + quar * 8) = src[0];
    *(float4*)(hq + row * 36 + quar * 8 + 4) = src[1];
  }
  __syncthreads();

  // ---- phase B: Q = Wq h + bq, hi/lo split into qf ----
  {
    int row = t >> 2, pr = t & 3;
    #pragma unroll
    for (int u = 0; u < 2; ++u) {
      int jj = pr * 2 + u;
      float a = bq[jj];
      #pragma unroll
      for (int d = 0; d < 32; ++d) a += hq[row * 36 + d] * wsq[d * 8 + jj];
      _Float16 qh = (_Float16)a;
      _Float16 ql = (_Float16)(a - (float)qh);
      qf[row * 16 + jj] = qh;
      qf[row * 16 + 8 + jj] = ql;
    }
  }
  __syncthreads();

  // ---- phase C: scores + softmax + PV ----
  const f16x8 hz = {(_Float16)0,(_Float16)0,(_Float16)0,(_Float16)0,
                    (_Float16)0,(_Float16)0,(_Float16)0,(_Float16)0};
  const f32x4 zf = {0.f, 0.f, 0.f, 0.f};
  _Float16* pls_ = (_Float16*)hq_pls;
  _Float16* myp = pls_ + wv * (16 * PSTR);
  const int q0 = qc * 64 + wv * 16;

  f16x8 aq = hz;
  if (g < 3) aq = *(const f16x8*)(qf + (wv * 16 + c) * 16 + (g & 1) * 8);

  f32x4 acc = {0.f, 0.f, 0.f, 0.f};
  float lsum[4] = {0.f, 0.f, 0.f, 0.f};

  for (int ch = 0; ch < 8; ++ch) {
    const int kb = ch * 64;
    #pragma unroll
    for (int kt = 0; kt < 4; ++kt) {
      f16x8 bk = hz;
      if (g < 2)       bk = *(const f16x8*)(khi + (kb + kt * 16 + c) * 8);
      else if (g == 2) bk = *(const f16x8*)(klo + (kb + kt * 16 + c) * 8);
      f32x4 s = __builtin_amdgcn_mfma_f32_16x16x32_f16(aq, bk, zf, 0, 0, 0);
      #pragma unroll
      for (int r = 0; r < 4; ++r) {
        float p = __expf(s[r] * 0.35355339059327373f - 2.0f);
        _Float16 ph = (_Float16)p;
        lsum[r] += (float)ph;
        myp[(g * 4 + r) * PSTR + kt * 16 + c] = ph;
      }
    }
    #pragma unroll
    for (int half = 0; half < 2; ++half) {
      f16x8 ap = *(const f16x8*)(myp + c * PSTR + half * 32 + g * 8);
      f16x8 bv = hz;
      if (c < 8) bv = *(const f16x8*)(vts + c * VSTR + kb + half * 32 + g * 8);
      acc = __builtin_amdgcn_mfma_f32_16x16x32_f16(ap, bv, acc, 0, 0, 0);
    }
  }
  #pragma unroll
  for (int m = 1; m < 16; m <<= 1) {
    #pragma unroll
    for (int r = 0; r < 4; ++r) lsum[r] += __shfl_xor(lsum[r], m, 64);
  }
  if (c < 8) {
    #pragma unroll
    for (int r = 0; r < 4; ++r) {
      float val = acc[r] / lsum[r];
      o[((q0 + g * 4 + r) * NP + n) * 32 + hh * 8 + c] = val;
    }
  }
}

// out-proj + residual + LN1, in-place on h. Block = 64 rows.
__global__ __launch_bounds__(256) void proj_ln1_kernel(
    const float* __restrict__ o, const float* __restrict__ wo, const float* __restrict__ bo,
    const float* __restrict__ lw, const float* __restrict__ lb, float* __restrict__ h) {
  __shared__ float wos[32 * 33];
  __shared__ float pre[64 * 33];
  const int g = blockIdx.x, t = threadIdx.x;
  for (int i = t; i < 1024; i += 256) wos[(i >> 5) * 33 + (i & 31)] = wo[i];
  __syncthreads();
  const int subr = t >> 2, jq = t & 3;
  const int r = g * 64 + subr;
  const float4* orow = (const float4*)(o + r * 32);
  float4 ov[8];
  #pragma unroll
  for (int i = 0; i < 8; ++i) ov[i] = orow[i];
  const float* hres = h + r * 32 + jq * 8;
  #pragma unroll
  for (int jj = 0; jj < 8; ++jj) {
    int j = jq * 8 + jj;
    float a0 = bo[j], a1 = 0.f, a2 = 0.f, a3 = 0.f;
    #pragma unroll
    for (int d4 = 0; d4 < 8; ++d4) {
      float4 vv = ov[d4];
      a0 += vv.x * wos[j * 33 + 4 * d4 + 0];
      a1 += vv.y * wos[j * 33 + 4 * d4 + 1];
      a2 += vv.z * wos[j * 33 + 4 * d4 + 2];
      a3 += vv.w * wos[j * 33 + 4 * d4 + 3];
    }
    pre[subr * 33 + j] = (a0 + a1) + (a2 + a3) + hres[jj];
  }
  __syncthreads();
  if (t < 64) {
    float mu = 0.f;
    #pragma unroll
    for (int d = 0; d < 32; ++d) mu += pre[t * 33 + d];
    mu *= (1.f / 32.f);
    float var = 0.f;
    #pragma unroll
    for (int d = 0; d < 32; ++d) { float dv = pre[t * 33 + d] - mu; var += dv * dv; }
    float rs = rsqrtf(var * (1.f / 32.f) + 1e-5f);
    float* hrow = h + (g * 64 + t) * 32;
    #pragma unroll
    for (int d = 0; d < 32; ++d)
      hrow[d] = (pre[t * 33 + d] - mu) * rs * lw[d] + lb[d];
  }
}

// Fused FF via fp16 MFMA. Block = 2 waves x 16 token rows; grid 768.
// A-fragments converted fp32->fp16 in-register from h (identical rounding
// to the old h16 buffer, which is now eliminated).
__global__ __launch_bounds__(128) void ff_mfma_kernel(
    const float* __restrict__ h, const _Float16* __restrict__ w1h,
    const float* __restrict__ b1, const _Float16* __restrict__ w2h,
    float* __restrict__ yp) {
  __shared__ alignas(16) _Float16 ubuf[2 * 16 * 40];
  const int t = threadIdx.x;
  const int lane = t & 63;
  const int wv = t >> 6;
  const int nl = lane & 15;
  const int g = lane >> 4;
  const int g4 = g * 4;
  const int r0 = blockIdx.x * 32 + wv * 16;
  _Float16* ub = ubuf + wv * 640;

  f16x8 hfrag;
  {
    const float4 h0 = *(const float4*)(h + (r0 + nl) * 32 + g * 8);
    const float4 h1 = *(const float4*)(h + (r0 + nl) * 32 + g * 8 + 4);
    hfrag[0] = (_Float16)h0.x; hfrag[1] = (_Float16)h0.y;
    hfrag[2] = (_Float16)h0.z; hfrag[3] = (_Float16)h0.w;
    hfrag[4] = (_Float16)h1.x; hfrag[5] = (_Float16)h1.y;
    hfrag[6] = (_Float16)h1.z; hfrag[7] = (_Float16)h1.w;
  }

  f32x4 acc0 = {0.f, 0.f, 0.f, 0.f};
  f32x4 acc1 = {0.f, 0.f, 0.f, 0.f};
  const f32x4 zero = {0.f, 0.f, 0.f, 0.f};

  for (int ch = 0; ch < 64; ++ch) {
    const int ffb = ch * 32;
    #pragma unroll
    for (int ft = 0; ft < 2; ++ft) {
      const int ffr = ffb + ft * 16;
      f16x8 afrag = *(const f16x8*)(w1h + (ffr + nl) * 32 + g * 8);
      f32x4 cc = __builtin_amdgcn_mfma_f32_16x16x32_f16(afrag, hfrag, zero, 0, 0, 0);
      float4 bv = *(const float4*)(b1 + ffr + g4);
      f16x4 uv;
      uv[0] = (_Float16)fmaxf(cc[0] + bv.x, 0.f);
      uv[1] = (_Float16)fmaxf(cc[1] + bv.y, 0.f);
      uv[2] = (_Float16)fmaxf(cc[2] + bv.z, 0.f);
      uv[3] = (_Float16)fmaxf(cc[3] + bv.w, 0.f);
      *(f16x4*)(ub + nl * 40 + ft * 16 + g4) = uv;
    }
    f16x8 ufrag = *(const f16x8*)(ub + nl * 40 + g * 8);
    {
      f16x8 b0 = *(const f16x8*)(w2h + nl * NFF + ffb + g * 8);
      acc0 = __builtin_amdgcn_mfma_f32_16x16x32_f16(ufrag, b0, acc0, 0, 0, 0);
      f16x8 b1f = *(const f16x8*)(w2h + (16 + nl) * NFF + ffb + g * 8);
      acc1 = __builtin_amdgcn_mfma_f32_16x16x32_f16(ufrag, b1f, acc1, 0, 0, 0);
    }
  }
  #pragma unroll
  for (int r = 0; r < 4; ++r) {
    yp[(r0 + g4 + r) * 32 + nl] = acc0[r];
    yp[(r0 + g4 + r) * 32 + 16 + nl] = acc1[r];
  }
}

// FF y + bias + residual + LN2 (in-place h); optionally svec.
__global__ __launch_bounds__(256) void ffred_ln2_kernel(
    const float* __restrict__ yp, const float* __restrict__ b2,
    const float* __restrict__ lw, const float* __restrict__ lb, float* __restrict__ h,
    const float* __restrict__ ow, const float* __restrict__ ob,
    float* __restrict__ svec, int do_svec) {
  __shared__ float pre[64 * 33];
  const int g = blockIdx.x, t = threadIdx.x;
  const int subr = t >> 2, jq = t & 3;
  const int r = g * 64 + subr;
  const float4* y0 = (const float4*)(yp + r * 32 + jq * 8);
  const float4* hres = (const float4*)(h + r * 32 + jq * 8);
  const float4* b2v = (const float4*)(b2 + jq * 8);
  #pragma unroll
  for (int i = 0; i < 2; ++i) {
    float4 a = y0[i], cc = hres[i], bb = b2v[i];
    pre[subr * 33 + jq * 8 + 4 * i + 0] = a.x + cc.x + bb.x;
    pre[subr * 33 + jq * 8 + 4 * i + 1] = a.y + cc.y + bb.y;
    pre[subr * 33 + jq * 8 + 4 * i + 2] = a.z + cc.z + bb.z;
    pre[subr * 33 + jq * 8 + 4 * i + 3] = a.w + cc.w + bb.w;
  }
  __syncthreads();
  if (t < 64) {
    float mu = 0.f;
    #pragma unroll
    for (int d = 0; d < 32; ++d) mu += pre[t * 33 + d];
    mu *= (1.f / 32.f);
    float var = 0.f;
    #pragma unroll
    for (int d = 0; d < 32; ++d) { float dv = pre[t * 33 + d] - mu; var += dv * dv; }
    float rs = rsqrtf(var * (1.f / 32.f) + 1e-5f);
    const int rr = g * 64 + t;
    float* hrow = h + rr * 32;
    float hn[32];
    #pragma unroll
    for (int d = 0; d < 32; ++d) {
      hn[d] = (pre[t * 33 + d] - mu) * rs * lw[d] + lb[d];
      hrow[d] = hn[d];
    }
    if (do_svec) {
      int l = rr / NP, n = rr - l * NP;
      if (n > 0) {
        float a = ob[0];
        #pragma unroll
        for (int d = 0; d < 32; ++d) a += hn[d] * ow[d];
        svec[l * NS + (n - 1)] = fmaxf(a, 0.f);
      }
    }
  }
}

// final MLP head per batch element
__global__ __launch_bounds__(256) void head_kernel(
    const float* __restrict__ svec,
    const float* __restrict__ m0w, const float* __restrict__ m0b,
    const float* __restrict__ m1w, const float* __restrict__ m1b,
    const float* __restrict__ m2w, const float* __restrict__ m2b,
    float* __restrict__ out) {
  __shared__ float sv[NS];
  __shared__ float hid[NHID];
  __shared__ float red[4];
  const int l = blockIdx.x, t = threadIdx.x;
  if (t < NS) sv[t] = svec[l * NS + t];
  __syncthreads();
  {
    float a = m0b[t];
    const float* wr = m0w + t * NS;
    #pragma unroll
    for (int s = 0; s < NS; ++s) a += sv[s] * wr[s];
    hid[t] = fmaxf(a, 0.f);
  }
  __syncthreads();
  {
    float a = m1b[t];
    const float4* wr = (const float4*)(m1w + t * NHID);
    #pragma unroll 8
    for (int j4 = 0; j4 < 64; ++j4) {
      float4 w = wr[j4];
      a += hid[4 * j4 + 0] * w.x + hid[4 * j4 + 1] * w.y
         + hid[4 * j4 + 2] * w.z + hid[4 * j4 + 3] * w.w;
    }
    float h2 = fmaxf(a, 0.f);
    float part = h2 * m2w[t];
    #pragma unroll
    for (int off = 32; off > 0; off >>= 1) part += __shfl_down(part, off, 64);
    if ((t & 63) == 0) red[t >> 6] = part;
  }
  __syncthreads();
  if (t == 0) out[l] = fmaxf(red[0] + red[1] + red[2] + red[3] + m2b[0], 0.f);
}

extern "C" void kernel_launch(void* const* d_in, const int* in_sizes, int n_in,
                              void* d_out, int out_size, void* d_ws, size_t ws_size,
                              hipStream_t stream) {
  (void)in_sizes; (void)n_in; (void)out_size; (void)ws_size;
  const float* x     = (const float*)d_in[0];
  const float* w_in  = (const float*)d_in[1];
  const float* b_in  = (const float*)d_in[2];
  const float* w_pos = (const float*)d_in[3];
  const float* b_pos = (const float*)d_in[4];
  const float* cls   = (const float*)d_in[5];
  const float* wi    = (const float*)d_in[6];
  const float* bi    = (const float*)d_in[7];
  const float* wo    = (const float*)d_in[8];
  const float* bo    = (const float*)d_in[9];
  const float* l1w   = (const float*)d_in[10];
  const float* l1b   = (const float*)d_in[11];
  const float* f1w   = (const float*)d_in[12];
  const float* f1b   = (const float*)d_in[13];
  const float* f2w   = (const float*)d_in[14];
  const float* f2b   = (const float*)d_in[15];
  const float* l2w   = (const float*)d_in[16];
  const float* l2b   = (const float*)d_in[17];
  const float* ow    = (const float*)d_in[18];
  const float* ob    = (const float*)d_in[19];
  const float* m0w   = (const float*)d_in[20];
  const float* m0b   = (const float*)d_in[21];
  const float* m1w   = (const float*)d_in[22];
  const float* m1b   = (const float*)d_in[23];
  const float* m2w   = (const float*)d_in[24];
  const float* m2b   = (const float*)d_in[25];
  float* out = (float*)d_out;

  // Workspace: 2907648 f32 = 11.09 MiB (== round-4's proven footprint).
  // R2 aliasing by lifetime: Kp (kv->attn) and yp (ff->ffred) share [0,786432);
  // Vt (kv->attn) sits in [786432, 1179648).
  float* ws   = (float*)d_ws;
  float* h    = ws;                           // [0, 786432)
  float* o    = ws + 786432;                  // [786432, 1572864)
  float* R2   = ws + 1572864;                 // [1572864, 2752512)
  float* yp   = R2;
  _Float16* Kp = (_Float16*)R2;
  _Float16* Vt = (_Float16*)(R2 + 786432);
  float* svec = ws + 2752512;                 // 24064
  _Float16* w1h = (_Float16*)(ws + 2776576);  // 65536 f32 slots
  _Float16* w2h = (_Float16*)(ws + 2842112);  // 65536 f32 slots -> end 2907648

  prep16_kernel<<<512, 256, 0, stream>>>(f1w, f2w, w1h, w2h);
  embed_kernel<<<3072, 256, 0, stream>>>(x, w_in, b_in, w_pos, b_pos, cls, h);
  for (int L = 0; L < 2; ++L) {
    kv_kernel<<<384, 256, 0, stream>>>(h, wi + L * 3072, bi + L * 96, Kp, Vt);
    attn_mfma_kernel<<<1536, 256, 0, stream>>>(h, wi + L * 3072, bi + L * 96, Kp, Vt, o);
    proj_ln1_kernel<<<384, 256, 0, stream>>>(o, wo + L * 1024, bo + L * 32,
                                             l1w + L * 32, l1b + L * 32, h);
    ff_mfma_kernel<<<768, 128, 0, stream>>>(h, w1h + L * 65536, f1b + L * NFF,
                                            w2h + L * 65536, yp);
    ffred_ln2_kernel<<<384, 256, 0, stream>>>(yp, f2b + L * 32, l2w + L * 32, l2b + L * 32,
                                              h, ow, ob, svec, L);
  }
  head_kernel<<<512, 256, 0, stream>>>(svec, m0w, m0b, m1w, m1b, m2w, m2b, out);
}